// Round 2
// baseline (1041.212 us; speedup 1.0000x reference)
//
#include <hip/hip_runtime.h>

#define N_NODES 50000
#define N_EDGES 800000
#define E_TOT (N_EDGES + N_NODES)
#define D 128
#define N_GRAPHS 64
#define NEG_SLOPE 0.2f

__device__ __forceinline__ float wave_max(float v) {
  #pragma unroll
  for (int off = 32; off > 0; off >>= 1) v = fmaxf(v, __shfl_xor(v, off));
  return v;
}
__device__ __forceinline__ float wave_sum(float v) {
  #pragma unroll
  for (int off = 32; off > 0; off >>= 1) v += __shfl_xor(v, off);
  return v;
}

// ---------------- CSR build ----------------
__global__ void k_count(const int* __restrict__ ei, int* __restrict__ cnt) {
  int e = blockIdx.x * blockDim.x + threadIdx.x;
  if (e >= E_TOT) return;
  int dst = (e < N_EDGES) ? ei[N_EDGES + e] : (e - N_EDGES);
  atomicAdd(&cnt[dst], 1);
}

__global__ __launch_bounds__(1024) void k_scan(const int* __restrict__ cnt,
                                               int* __restrict__ rowptr) {
  __shared__ int sm[1024];
  int running = 0;
  if (threadIdx.x == 0) rowptr[0] = 0;
  for (int base = 0; base < N_NODES; base += 1024) {
    int i = base + threadIdx.x;
    int v = (i < N_NODES) ? cnt[i] : 0;
    sm[threadIdx.x] = v;
    __syncthreads();
    #pragma unroll
    for (int off = 1; off < 1024; off <<= 1) {
      int t = (threadIdx.x >= off) ? sm[threadIdx.x - off] : 0;
      __syncthreads();
      sm[threadIdx.x] += t;
      __syncthreads();
    }
    int incl = sm[threadIdx.x];
    if (i < N_NODES) rowptr[i + 1] = running + incl;
    running += sm[1023];
    __syncthreads();
  }
}

__global__ void k_fill(const int* __restrict__ ei, const int* __restrict__ rowptr,
                       int* __restrict__ fill, int* __restrict__ col) {
  int e = blockIdx.x * blockDim.x + threadIdx.x;
  if (e >= E_TOT) return;
  int src, dst;
  if (e < N_EDGES) { src = ei[e]; dst = ei[N_EDGES + e]; }
  else { src = e - N_EDGES; dst = src; }
  int pos = rowptr[dst] + atomicAdd(&fill[dst], 1);
  col[pos] = src;
}

// ---------------- GEMM: H = X @ W (fp32, 64x128 tile) ----------------
__global__ __launch_bounds__(256) void k_gemm(const float* __restrict__ X,
                                              const float* __restrict__ W,
                                              float* __restrict__ H) {
  __shared__ float Xs[32][64];   // [k][m] transposed
  __shared__ float Ws[32][128];  // [k][n]
  const int tid = threadIdx.x;
  const int cg = tid & 15;   // 16 col groups of 8
  const int rg = tid >> 4;   // 16 row groups of 4
  const int rowbase = blockIdx.x * 64;
  const int r0 = rg * 4;
  const int c0 = cg * 8;
  float acc[4][8];
  #pragma unroll
  for (int i = 0; i < 4; i++)
    #pragma unroll
    for (int j = 0; j < 8; j++) acc[i][j] = 0.f;

  for (int kt = 0; kt < 4; ++kt) {
    #pragma unroll
    for (int i = 0; i < 2; i++) {
      int e = tid + i * 256;           // 0..511 float4s of X tile
      int row = e >> 3, kq = e & 7;
      int grow = rowbase + row;
      float4 f = make_float4(0.f, 0.f, 0.f, 0.f);
      if (grow < N_NODES)
        f = *reinterpret_cast<const float4*>(&X[(size_t)grow * D + kt * 32 + kq * 4]);
      Xs[kq * 4 + 0][row] = f.x;
      Xs[kq * 4 + 1][row] = f.y;
      Xs[kq * 4 + 2][row] = f.z;
      Xs[kq * 4 + 3][row] = f.w;
    }
    #pragma unroll
    for (int i = 0; i < 4; i++) {
      int e = tid + i * 256;           // 0..1023 float4s of W tile
      int kr = e >> 5, cq = e & 31;
      *reinterpret_cast<float4*>(&Ws[kr][cq * 4]) =
          *reinterpret_cast<const float4*>(&W[(size_t)(kt * 32 + kr) * D + cq * 4]);
    }
    __syncthreads();
    #pragma unroll
    for (int k = 0; k < 32; k++) {
      float4 a = *reinterpret_cast<const float4*>(&Xs[k][r0]);
      float4 b0 = *reinterpret_cast<const float4*>(&Ws[k][c0]);
      float4 b1 = *reinterpret_cast<const float4*>(&Ws[k][c0 + 4]);
      float av[4] = {a.x, a.y, a.z, a.w};
      float bv[8] = {b0.x, b0.y, b0.z, b0.w, b1.x, b1.y, b1.z, b1.w};
      #pragma unroll
      for (int i = 0; i < 4; i++)
        #pragma unroll
        for (int j = 0; j < 8; j++)
          acc[i][j] = fmaf(av[i], bv[j], acc[i][j]);
    }
    __syncthreads();
  }
  #pragma unroll
  for (int i = 0; i < 4; i++) {
    int grow = rowbase + r0 + i;
    if (grow < N_NODES) {
      *reinterpret_cast<float4*>(&H[(size_t)grow * D + c0]) =
          make_float4(acc[i][0], acc[i][1], acc[i][2], acc[i][3]);
      *reinterpret_cast<float4*>(&H[(size_t)grow * D + c0 + 4]) =
          make_float4(acc[i][4], acc[i][5], acc[i][6], acc[i][7]);
    }
  }
}

// ---------------- per-node attention dots ----------------
__global__ __launch_bounds__(256) void k_alpha(const float* __restrict__ H,
                                               const float* __restrict__ asrc,
                                               const float* __restrict__ adst,
                                               float* __restrict__ alpha_s,
                                               float* __restrict__ alpha_d) {
  int wid = threadIdx.x >> 6;
  int lane = threadIdx.x & 63;
  int node = blockIdx.x * 4 + wid;
  if (node >= N_NODES) return;
  float2 h = *reinterpret_cast<const float2*>(&H[(size_t)node * D + lane * 2]);
  float2 as = *reinterpret_cast<const float2*>(&asrc[lane * 2]);
  float2 ad = *reinterpret_cast<const float2*>(&adst[lane * 2]);
  float s = h.x * as.x + h.y * as.y;
  float d = h.x * ad.x + h.y * ad.y;
  s = wave_sum(s);
  d = wave_sum(d);
  if (lane == 0) {
    alpha_s[node] = s;
    alpha_d[node] = d;
  }
}

// ---------------- fused segment softmax + aggregate + bias + relu ----------------
// FINAL=1: instead of writing the output row, dot with fcW and atomically
// accumulate into gsum[batch[node]] (mean-pool + FC fusion).
template <int FINAL>
__global__ __launch_bounds__(256) void k_agg(const float* __restrict__ H,
                                             const int* __restrict__ rowptr,
                                             const int* __restrict__ col,
                                             const float* __restrict__ alpha_s,
                                             const float* __restrict__ alpha_d,
                                             const float* __restrict__ bias,
                                             float* __restrict__ Out,
                                             const float* __restrict__ fcW,
                                             const int* __restrict__ batch,
                                             float* __restrict__ gsum) {
  int wid = threadIdx.x >> 6;
  int lane = threadIdx.x & 63;
  int node = blockIdx.x * 4 + wid;
  if (node >= N_NODES) return;
  int start = rowptr[node], end = rowptr[node + 1];
  float ad = alpha_d[node];

  float m = -1e30f;
  for (int base = start; base < end; base += 64) {
    int j = base + lane;
    if (j < end) {
      float e = alpha_s[col[j]] + ad;
      e = e >= 0.f ? e : NEG_SLOPE * e;
      m = fmaxf(m, e);
    }
  }
  m = wave_max(m);

  float dsum = 0.f;
  for (int base = start; base < end; base += 64) {
    int j = base + lane;
    if (j < end) {
      float e = alpha_s[col[j]] + ad;
      e = e >= 0.f ? e : NEG_SLOPE * e;
      dsum += expf(e - m);
    }
  }
  dsum = wave_sum(dsum);
  float inv = 1.f / (dsum + 1e-16f);

  float2 acc = make_float2(0.f, 0.f);
  for (int j = start; j < end; ++j) {
    int s = col[j];
    float e = alpha_s[s] + ad;
    e = e >= 0.f ? e : NEG_SLOPE * e;
    float w = expf(e - m);
    float2 hv = *reinterpret_cast<const float2*>(&H[(size_t)s * D + lane * 2]);
    acc.x = fmaf(w, hv.x, acc.x);
    acc.y = fmaf(w, hv.y, acc.y);
  }
  float2 bv = *reinterpret_cast<const float2*>(&bias[lane * 2]);
  float ox = fmaxf(acc.x * inv + bv.x, 0.f);
  float oy = fmaxf(acc.y * inv + bv.y, 0.f);
  if (FINAL) {
    float2 wv = *reinterpret_cast<const float2*>(&fcW[lane * 2]);
    float y = wave_sum(ox * wv.x + oy * wv.y);
    if (lane == 0) atomicAdd(&gsum[batch[node]], y);
  } else {
    *reinterpret_cast<float2*>(&Out[(size_t)node * D + lane * 2]) = make_float2(ox, oy);
  }
}

// ---------------- finalize: divide by counts, add bias ----------------
__global__ void k_final(const float* __restrict__ gsum, const int* __restrict__ batch,
                        const float* __restrict__ fcb, float* __restrict__ out) {
  int b = threadIdx.x;
  if (b >= N_GRAPHS) return;
  int lo = 0, hi = N_NODES;
  while (lo < hi) { int mid = (lo + hi) >> 1; if (batch[mid] < b) lo = mid + 1; else hi = mid; }
  int s0 = lo;
  lo = 0; hi = N_NODES;
  while (lo < hi) { int mid = (lo + hi) >> 1; if (batch[mid] < b + 1) lo = mid + 1; else hi = mid; }
  int s1 = lo;
  float cntf = (float)(s1 - s0);
  out[b] = gsum[b] / fmaxf(cntf, 1.f) + fcb[0];
}

extern "C" void kernel_launch(void* const* d_in, const int* in_sizes, int n_in,
                              void* d_out, int out_size, void* d_ws, size_t ws_size,
                              hipStream_t stream) {
  const float* x = (const float*)d_in[0];
  const int* ei = (const int*)d_in[1];
  const int* batch = (const int*)d_in[2];
  const float* W[4]   = {(const float*)d_in[3], (const float*)d_in[7],
                         (const float*)d_in[11], (const float*)d_in[15]};
  const float* asr[4] = {(const float*)d_in[4], (const float*)d_in[8],
                         (const float*)d_in[12], (const float*)d_in[16]};
  const float* adt[4] = {(const float*)d_in[5], (const float*)d_in[9],
                         (const float*)d_in[13], (const float*)d_in[17]};
  const float* bs[4]  = {(const float*)d_in[6], (const float*)d_in[10],
                         (const float*)d_in[14], (const float*)d_in[18]};
  const float* fcW = (const float*)d_in[19];
  const float* fcb = (const float*)d_in[20];
  float* out = (float*)d_out;

  char* ws = (char*)d_ws;
  size_t off = 0;
  float* hA = (float*)(ws + off); off += (size_t)N_NODES * D * 4;     // gemm out
  float* hB = (float*)(ws + off); off += (size_t)N_NODES * D * 4;     // layer out
  float* alpha_s = (float*)(ws + off); off += (size_t)N_NODES * 4;
  float* alpha_d = (float*)(ws + off); off += (size_t)N_NODES * 4;
  int* cnt  = (int*)(ws + off); off += (size_t)N_NODES * 4;
  int* fill = (int*)(ws + off); off += (size_t)N_NODES * 4;           // contiguous after cnt
  int* rowptr = (int*)(ws + off); off += (size_t)(N_NODES + 1) * 4 + 12;
  int* col = (int*)(ws + off); off += (size_t)E_TOT * 4;
  float* gsum = (float*)(ws + off); off += (size_t)N_GRAPHS * 4;
  (void)ws_size; (void)in_sizes; (void)n_in; (void)out_size;

  hipMemsetAsync(cnt, 0, (size_t)N_NODES * 4 * 2, stream);  // zero cnt + fill
  hipMemsetAsync(gsum, 0, (size_t)N_GRAPHS * 4, stream);
  int eb = (E_TOT + 255) / 256;
  k_count<<<eb, 256, 0, stream>>>(ei, cnt);
  k_scan<<<1, 1024, 0, stream>>>(cnt, rowptr);
  k_fill<<<eb, 256, 0, stream>>>(ei, rowptr, fill, col);

  const float* in = x;
  for (int l = 0; l < 4; ++l) {
    k_gemm<<<(N_NODES + 63) / 64, 256, 0, stream>>>(in, W[l], hA);
    k_alpha<<<(N_NODES + 3) / 4, 256, 0, stream>>>(hA, asr[l], adt[l], alpha_s, alpha_d);
    if (l < 3) {
      k_agg<0><<<(N_NODES + 3) / 4, 256, 0, stream>>>(hA, rowptr, col, alpha_s, alpha_d,
                                                      bs[l], hB, nullptr, nullptr, nullptr);
    } else {
      k_agg<1><<<(N_NODES + 3) / 4, 256, 0, stream>>>(hA, rowptr, col, alpha_s, alpha_d,
                                                      bs[l], nullptr, fcW, batch, gsum);
    }
    in = hB;
  }
  k_final<<<1, 64, 0, stream>>>(gsum, batch, fcb, out);
}

// Round 3
// 573.955 us; speedup vs baseline: 1.8141x; 1.8141x over previous
//
#include <hip/hip_runtime.h>

#define N_NODES 50000
#define N_EDGES 800000
#define E_TOT (N_EDGES + N_NODES)
#define D 128
#define N_GRAPHS 64
#define NEG_SLOPE 0.2f
#define MAXDEG 256   // LDS weight-cache capacity per node (avg degree ~17)

__device__ __forceinline__ float wave_max(float v) {
  #pragma unroll
  for (int off = 32; off > 0; off >>= 1) v = fmaxf(v, __shfl_xor(v, off));
  return v;
}
__device__ __forceinline__ float wave_sum(float v) {
  #pragma unroll
  for (int off = 32; off > 0; off >>= 1) v += __shfl_xor(v, off);
  return v;
}

// ---------------- CSR build ----------------
__global__ void k_count(const int* __restrict__ ei, int* __restrict__ cnt) {
  int e = blockIdx.x * blockDim.x + threadIdx.x;
  if (e >= E_TOT) return;
  int dst = (e < N_EDGES) ? ei[N_EDGES + e] : (e - N_EDGES);
  atomicAdd(&cnt[dst], 1);
}

__global__ __launch_bounds__(1024) void k_scan(const int* __restrict__ cnt,
                                               int* __restrict__ rowptr) {
  __shared__ int sm[1024];
  int running = 0;
  if (threadIdx.x == 0) rowptr[0] = 0;
  for (int base = 0; base < N_NODES; base += 1024) {
    int i = base + threadIdx.x;
    int v = (i < N_NODES) ? cnt[i] : 0;
    sm[threadIdx.x] = v;
    __syncthreads();
    #pragma unroll
    for (int off = 1; off < 1024; off <<= 1) {
      int t = (threadIdx.x >= off) ? sm[threadIdx.x - off] : 0;
      __syncthreads();
      sm[threadIdx.x] += t;
      __syncthreads();
    }
    int incl = sm[threadIdx.x];
    if (i < N_NODES) rowptr[i + 1] = running + incl;
    running += sm[1023];
    __syncthreads();
  }
}

__global__ void k_fill(const int* __restrict__ ei, const int* __restrict__ rowptr,
                       int* __restrict__ fill, int* __restrict__ col) {
  int e = blockIdx.x * blockDim.x + threadIdx.x;
  if (e >= E_TOT) return;
  int src, dst;
  if (e < N_EDGES) { src = ei[e]; dst = ei[N_EDGES + e]; }
  else { src = e - N_EDGES; dst = src; }
  int pos = rowptr[dst] + atomicAdd(&fill[dst], 1);
  col[pos] = src;
}

// ---------------- GEMM: H = X @ W (fp32, 64x128 tile) ----------------
__global__ __launch_bounds__(256) void k_gemm(const float* __restrict__ X,
                                              const float* __restrict__ W,
                                              float* __restrict__ H) {
  __shared__ float Xs[32][64];   // [k][m] transposed
  __shared__ float Ws[32][128];  // [k][n]
  const int tid = threadIdx.x;
  const int cg = tid & 15;   // 16 col groups of 8
  const int rg = tid >> 4;   // 16 row groups of 4
  const int rowbase = blockIdx.x * 64;
  const int r0 = rg * 4;
  const int c0 = cg * 8;
  float acc[4][8];
  #pragma unroll
  for (int i = 0; i < 4; i++)
    #pragma unroll
    for (int j = 0; j < 8; j++) acc[i][j] = 0.f;

  for (int kt = 0; kt < 4; ++kt) {
    #pragma unroll
    for (int i = 0; i < 2; i++) {
      int e = tid + i * 256;           // 0..511 float4s of X tile
      int row = e >> 3, kq = e & 7;
      int grow = rowbase + row;
      float4 f = make_float4(0.f, 0.f, 0.f, 0.f);
      if (grow < N_NODES)
        f = *reinterpret_cast<const float4*>(&X[(size_t)grow * D + kt * 32 + kq * 4]);
      Xs[kq * 4 + 0][row] = f.x;
      Xs[kq * 4 + 1][row] = f.y;
      Xs[kq * 4 + 2][row] = f.z;
      Xs[kq * 4 + 3][row] = f.w;
    }
    #pragma unroll
    for (int i = 0; i < 4; i++) {
      int e = tid + i * 256;           // 0..1023 float4s of W tile
      int kr = e >> 5, cq = e & 31;
      *reinterpret_cast<float4*>(&Ws[kr][cq * 4]) =
          *reinterpret_cast<const float4*>(&W[(size_t)(kt * 32 + kr) * D + cq * 4]);
    }
    __syncthreads();
    #pragma unroll
    for (int k = 0; k < 32; k++) {
      float4 a = *reinterpret_cast<const float4*>(&Xs[k][r0]);
      float4 b0 = *reinterpret_cast<const float4*>(&Ws[k][c0]);
      float4 b1 = *reinterpret_cast<const float4*>(&Ws[k][c0 + 4]);
      float av[4] = {a.x, a.y, a.z, a.w};
      float bv[8] = {b0.x, b0.y, b0.z, b0.w, b1.x, b1.y, b1.z, b1.w};
      #pragma unroll
      for (int i = 0; i < 4; i++)
        #pragma unroll
        for (int j = 0; j < 8; j++)
          acc[i][j] = fmaf(av[i], bv[j], acc[i][j]);
    }
    __syncthreads();
  }
  #pragma unroll
  for (int i = 0; i < 4; i++) {
    int grow = rowbase + r0 + i;
    if (grow < N_NODES) {
      *reinterpret_cast<float4*>(&H[(size_t)grow * D + c0]) =
          make_float4(acc[i][0], acc[i][1], acc[i][2], acc[i][3]);
      *reinterpret_cast<float4*>(&H[(size_t)grow * D + c0 + 4]) =
          make_float4(acc[i][4], acc[i][5], acc[i][6], acc[i][7]);
    }
  }
}

// ---------------- per-node attention dots ----------------
__global__ __launch_bounds__(256) void k_alpha(const float* __restrict__ H,
                                               const float* __restrict__ asrc,
                                               const float* __restrict__ adst,
                                               float* __restrict__ alpha_s,
                                               float* __restrict__ alpha_d) {
  int wid = threadIdx.x >> 6;
  int lane = threadIdx.x & 63;
  int node = blockIdx.x * 4 + wid;
  if (node >= N_NODES) return;
  float2 h = *reinterpret_cast<const float2*>(&H[(size_t)node * D + lane * 2]);
  float2 as = *reinterpret_cast<const float2*>(&asrc[lane * 2]);
  float2 ad = *reinterpret_cast<const float2*>(&adst[lane * 2]);
  float s = h.x * as.x + h.y * as.y;
  float d = h.x * ad.x + h.y * ad.y;
  s = wave_sum(s);
  d = wave_sum(d);
  if (lane == 0) {
    alpha_s[node] = s;
    alpha_d[node] = d;
  }
}

// ---------------- fused segment softmax + aggregate + bias + relu ----------------
// Weights & cols cached in LDS (per-wave slice); gather loop unrolled x8 for MLP.
// FINAL=1: dot with fcW, write per-node scalar to ynode (no atomics).
template <int FINAL>
__global__ __launch_bounds__(256) void k_agg(const float* __restrict__ H,
                                             const int* __restrict__ rowptr,
                                             const int* __restrict__ col,
                                             const float* __restrict__ alpha_s,
                                             const float* __restrict__ alpha_d,
                                             const float* __restrict__ bias,
                                             float* __restrict__ Out,
                                             const float* __restrict__ fcW,
                                             float* __restrict__ ynode) {
  __shared__ float wls[4][MAXDEG];
  __shared__ int cls[4][MAXDEG];
  int wid = threadIdx.x >> 6;
  int lane = threadIdx.x & 63;
  int node = blockIdx.x * 4 + wid;
  if (node >= N_NODES) return;
  int start = rowptr[node], end = rowptr[node + 1];
  int deg = end - start;
  float ad = alpha_d[node];

  // pass 1: e into registers (lane-strided) + cols into LDS, wave max
  float earr[4];
  float m = -1e30f;
  #pragma unroll
  for (int k = 0; k < 4; ++k) {
    int j0 = lane + k * 64;
    earr[k] = -1e30f;
    if (j0 < deg) {
      int s = col[start + j0];
      float e = alpha_s[s] + ad;
      e = e >= 0.f ? e : NEG_SLOPE * e;
      cls[wid][j0] = s;
      earr[k] = e;
    }
  }
  m = fmaxf(fmaxf(earr[0], earr[1]), fmaxf(earr[2], earr[3]));
  for (int j0 = MAXDEG + lane; j0 < deg; j0 += 64) {   // cold fallback
    int s = col[start + j0];
    float e = alpha_s[s] + ad;
    e = e >= 0.f ? e : NEG_SLOPE * e;
    m = fmaxf(m, e);
  }
  m = wave_max(m);

  // pass 2: weights into LDS, wave sum
  float dsum = 0.f;
  #pragma unroll
  for (int k = 0; k < 4; ++k) {
    int j0 = lane + k * 64;
    if (j0 < deg) {
      float w = expf(earr[k] - m);
      wls[wid][j0] = w;
      dsum += w;
    }
  }
  for (int j0 = MAXDEG + lane; j0 < deg; j0 += 64) {   // cold fallback
    int s = col[start + j0];
    float e = alpha_s[s] + ad;
    e = e >= 0.f ? e : NEG_SLOPE * e;
    dsum += expf(e - m);
  }
  dsum = wave_sum(dsum);
  float inv = 1.f / (dsum + 1e-16f);

  // pass 3: gather, 8 independent row loads per step (weights via LDS broadcast)
  float2 acc = make_float2(0.f, 0.f);
  int degc = deg < MAXDEG ? deg : MAXDEG;
  int jj = 0;
  for (; jj + 8 <= degc; jj += 8) {
    float w[8];
    float2 hv[8];
    #pragma unroll
    for (int u = 0; u < 8; ++u) {
      int s = cls[wid][jj + u];
      w[u] = wls[wid][jj + u];
      hv[u] = *reinterpret_cast<const float2*>(&H[(size_t)s * D + lane * 2]);
    }
    #pragma unroll
    for (int u = 0; u < 8; ++u) {
      acc.x = fmaf(w[u], hv[u].x, acc.x);
      acc.y = fmaf(w[u], hv[u].y, acc.y);
    }
  }
  for (; jj < deg; ++jj) {
    int s;
    float w;
    if (jj < MAXDEG) {
      s = cls[wid][jj];
      w = wls[wid][jj];
    } else {                                            // cold fallback
      s = col[start + jj];
      float e = alpha_s[s] + ad;
      e = e >= 0.f ? e : NEG_SLOPE * e;
      w = expf(e - m);
    }
    float2 hv = *reinterpret_cast<const float2*>(&H[(size_t)s * D + lane * 2]);
    acc.x = fmaf(w, hv.x, acc.x);
    acc.y = fmaf(w, hv.y, acc.y);
  }

  float2 bv = *reinterpret_cast<const float2*>(&bias[lane * 2]);
  float ox = fmaxf(acc.x * inv + bv.x, 0.f);
  float oy = fmaxf(acc.y * inv + bv.y, 0.f);
  if (FINAL) {
    float2 wv = *reinterpret_cast<const float2*>(&fcW[lane * 2]);
    float y = wave_sum(ox * wv.x + oy * wv.y);
    if (lane == 0) ynode[node] = y;
  } else {
    *reinterpret_cast<float2*>(&Out[(size_t)node * D + lane * 2]) = make_float2(ox, oy);
  }
}

// ---------------- finalize: per-graph mean of ynode + bias ----------------
__global__ __launch_bounds__(256) void k_final(const float* __restrict__ ynode,
                                               const int* __restrict__ batch,
                                               const float* __restrict__ fcb,
                                               float* __restrict__ out) {
  __shared__ float sm[256];
  int b = blockIdx.x;
  int tid = threadIdx.x;
  int lo = 0, hi = N_NODES;
  while (lo < hi) { int mid = (lo + hi) >> 1; if (batch[mid] < b) lo = mid + 1; else hi = mid; }
  int s0 = lo;
  lo = 0; hi = N_NODES;
  while (lo < hi) { int mid = (lo + hi) >> 1; if (batch[mid] < b + 1) lo = mid + 1; else hi = mid; }
  int s1 = lo;
  float sum = 0.f;
  for (int n = s0 + tid; n < s1; n += 256) sum += ynode[n];
  sm[tid] = sum;
  __syncthreads();
  #pragma unroll
  for (int off = 128; off > 0; off >>= 1) {
    if (tid < off) sm[tid] += sm[tid + off];
    __syncthreads();
  }
  if (tid == 0) out[b] = sm[0] / fmaxf((float)(s1 - s0), 1.f) + fcb[0];
}

extern "C" void kernel_launch(void* const* d_in, const int* in_sizes, int n_in,
                              void* d_out, int out_size, void* d_ws, size_t ws_size,
                              hipStream_t stream) {
  const float* x = (const float*)d_in[0];
  const int* ei = (const int*)d_in[1];
  const int* batch = (const int*)d_in[2];
  const float* W[4]   = {(const float*)d_in[3], (const float*)d_in[7],
                         (const float*)d_in[11], (const float*)d_in[15]};
  const float* asr[4] = {(const float*)d_in[4], (const float*)d_in[8],
                         (const float*)d_in[12], (const float*)d_in[16]};
  const float* adt[4] = {(const float*)d_in[5], (const float*)d_in[9],
                         (const float*)d_in[13], (const float*)d_in[17]};
  const float* bs[4]  = {(const float*)d_in[6], (const float*)d_in[10],
                         (const float*)d_in[14], (const float*)d_in[18]};
  const float* fcW = (const float*)d_in[19];
  const float* fcb = (const float*)d_in[20];
  float* out = (float*)d_out;

  char* ws = (char*)d_ws;
  size_t off = 0;
  float* hA = (float*)(ws + off); off += (size_t)N_NODES * D * 4;     // gemm out
  float* hB = (float*)(ws + off); off += (size_t)N_NODES * D * 4;     // layer out
  float* alpha_s = (float*)(ws + off); off += (size_t)N_NODES * 4;
  float* alpha_d = (float*)(ws + off); off += (size_t)N_NODES * 4;
  int* cnt  = (int*)(ws + off); off += (size_t)N_NODES * 4;
  int* fill = (int*)(ws + off); off += (size_t)N_NODES * 4;           // contiguous after cnt
  int* rowptr = (int*)(ws + off); off += (size_t)(N_NODES + 1) * 4 + 12;
  int* col = (int*)(ws + off); off += (size_t)E_TOT * 4;
  float* ynode = (float*)(ws + off); off += (size_t)N_NODES * 4;
  (void)ws_size; (void)in_sizes; (void)n_in; (void)out_size;

  hipMemsetAsync(cnt, 0, (size_t)N_NODES * 4 * 2, stream);  // zero cnt + fill
  int eb = (E_TOT + 255) / 256;
  k_count<<<eb, 256, 0, stream>>>(ei, cnt);
  k_scan<<<1, 1024, 0, stream>>>(cnt, rowptr);
  k_fill<<<eb, 256, 0, stream>>>(ei, rowptr, fill, col);

  const float* in = x;
  for (int l = 0; l < 4; ++l) {
    k_gemm<<<(N_NODES + 63) / 64, 256, 0, stream>>>(in, W[l], hA);
    k_alpha<<<(N_NODES + 3) / 4, 256, 0, stream>>>(hA, asr[l], adt[l], alpha_s, alpha_d);
    if (l < 3) {
      k_agg<0><<<(N_NODES + 3) / 4, 256, 0, stream>>>(hA, rowptr, col, alpha_s, alpha_d,
                                                      bs[l], hB, nullptr, nullptr);
    } else {
      k_agg<1><<<(N_NODES + 3) / 4, 256, 0, stream>>>(hA, rowptr, col, alpha_s, alpha_d,
                                                      bs[l], nullptr, fcW, ynode);
    }
    in = hB;
  }
  k_final<<<N_GRAPHS, 256, 0, stream>>>(ynode, batch, fcb, out);
}

// Round 4
// 471.061 us; speedup vs baseline: 2.2104x; 1.2184x over previous
//
#include <hip/hip_runtime.h>

#define N_NODES 50000
#define N_EDGES 800000
#define E_TOT (N_EDGES + N_NODES)
#define D 128
#define N_GRAPHS 64
#define NEG_SLOPE 0.2f
#define MAXDEG 256   // LDS weight-cache capacity per node (avg degree ~17)
#define SCAN_BLK 1024
#define SCAN_GRID ((N_NODES + SCAN_BLK - 1) / SCAN_BLK)   // 49

__device__ __forceinline__ float wave_max(float v) {
  #pragma unroll
  for (int off = 32; off > 0; off >>= 1) v = fmaxf(v, __shfl_xor(v, off));
  return v;
}
__device__ __forceinline__ float wave_sum(float v) {
  #pragma unroll
  for (int off = 32; off > 0; off >>= 1) v += __shfl_xor(v, off);
  return v;
}

// ---------------- CSR build ----------------
__global__ void k_count(const int* __restrict__ ei, int* __restrict__ cnt) {
  int e = blockIdx.x * blockDim.x + threadIdx.x;
  if (e >= E_TOT) return;
  int dst = (e < N_EDGES) ? ei[N_EDGES + e] : (e - N_EDGES);
  atomicAdd(&cnt[dst], 1);
}

// hierarchical scan: per-block inclusive scan + block totals
__global__ __launch_bounds__(SCAN_BLK) void k_scan1(const int* __restrict__ cnt,
                                                    int* __restrict__ rowptr,
                                                    int* __restrict__ partial) {
  __shared__ int sm[SCAN_BLK];
  int i = blockIdx.x * SCAN_BLK + threadIdx.x;
  int v = (i < N_NODES) ? cnt[i] : 0;
  sm[threadIdx.x] = v;
  __syncthreads();
  #pragma unroll
  for (int off = 1; off < SCAN_BLK; off <<= 1) {
    int t = (threadIdx.x >= off) ? sm[threadIdx.x - off] : 0;
    __syncthreads();
    sm[threadIdx.x] += t;
    __syncthreads();
  }
  if (i < N_NODES) rowptr[i + 1] = sm[threadIdx.x];
  if (threadIdx.x == SCAN_BLK - 1) partial[blockIdx.x] = sm[threadIdx.x];
}

// scan the 49 block totals with one wave
__global__ void k_scan2(int* __restrict__ partial) {
  int lane = threadIdx.x;
  int v = (lane < SCAN_GRID) ? partial[lane] : 0;
  #pragma unroll
  for (int off = 1; off < 64; off <<= 1) {
    int t = __shfl_up(v, off);
    if (lane >= off) v += t;
  }
  if (lane < SCAN_GRID) partial[lane] = v;
}

__global__ __launch_bounds__(SCAN_BLK) void k_scan3(int* __restrict__ rowptr,
                                                    const int* __restrict__ partial) {
  int i = blockIdx.x * SCAN_BLK + threadIdx.x;
  if (i == 0) rowptr[0] = 0;
  if (i < N_NODES && blockIdx.x > 0) rowptr[i + 1] += partial[blockIdx.x - 1];
}

__global__ void k_fill(const int* __restrict__ ei, const int* __restrict__ rowptr,
                       int* __restrict__ fill, int* __restrict__ col) {
  int e = blockIdx.x * blockDim.x + threadIdx.x;
  if (e >= E_TOT) return;
  int src, dst;
  if (e < N_EDGES) { src = ei[e]; dst = ei[N_EDGES + e]; }
  else { src = e - N_EDGES; dst = src; }
  int pos = rowptr[dst] + atomicAdd(&fill[dst], 1);
  col[pos] = src;
}

// ---------------- GEMM: H = X @ W (fp32, 64x128 tile) + fused alpha dots ----------------
__global__ __launch_bounds__(256) void k_gemm(const float* __restrict__ X,
                                              const float* __restrict__ W,
                                              float* __restrict__ H,
                                              const float* __restrict__ asrc,
                                              const float* __restrict__ adst,
                                              float* __restrict__ alpha_s,
                                              float* __restrict__ alpha_d) {
  __shared__ float Xs[32][64];   // [k][m] transposed
  __shared__ float Ws[32][128];  // [k][n]
  const int tid = threadIdx.x;
  const int cg = tid & 15;   // 16 col groups of 8
  const int rg = tid >> 4;   // 16 row groups of 4
  const int rowbase = blockIdx.x * 64;
  const int r0 = rg * 4;
  const int c0 = cg * 8;
  float acc[4][8];
  #pragma unroll
  for (int i = 0; i < 4; i++)
    #pragma unroll
    for (int j = 0; j < 8; j++) acc[i][j] = 0.f;

  for (int kt = 0; kt < 4; ++kt) {
    #pragma unroll
    for (int i = 0; i < 2; i++) {
      int e = tid + i * 256;           // 0..511 float4s of X tile
      int row = e >> 3, kq = e & 7;
      int grow = rowbase + row;
      float4 f = make_float4(0.f, 0.f, 0.f, 0.f);
      if (grow < N_NODES)
        f = *reinterpret_cast<const float4*>(&X[(size_t)grow * D + kt * 32 + kq * 4]);
      Xs[kq * 4 + 0][row] = f.x;
      Xs[kq * 4 + 1][row] = f.y;
      Xs[kq * 4 + 2][row] = f.z;
      Xs[kq * 4 + 3][row] = f.w;
    }
    #pragma unroll
    for (int i = 0; i < 4; i++) {
      int e = tid + i * 256;           // 0..1023 float4s of W tile
      int kr = e >> 5, cq = e & 31;
      *reinterpret_cast<float4*>(&Ws[kr][cq * 4]) =
          *reinterpret_cast<const float4*>(&W[(size_t)(kt * 32 + kr) * D + cq * 4]);
    }
    __syncthreads();
    #pragma unroll
    for (int k = 0; k < 32; k++) {
      float4 a = *reinterpret_cast<const float4*>(&Xs[k][r0]);
      float4 b0 = *reinterpret_cast<const float4*>(&Ws[k][c0]);
      float4 b1 = *reinterpret_cast<const float4*>(&Ws[k][c0 + 4]);
      float av[4] = {a.x, a.y, a.z, a.w};
      float bv[8] = {b0.x, b0.y, b0.z, b0.w, b1.x, b1.y, b1.z, b1.w};
      #pragma unroll
      for (int i = 0; i < 4; i++)
        #pragma unroll
        for (int j = 0; j < 8; j++)
          acc[i][j] = fmaf(av[i], bv[j], acc[i][j]);
    }
    __syncthreads();
  }

  // attention dot vectors for this thread's 8 columns
  float4 as0 = *reinterpret_cast<const float4*>(&asrc[c0]);
  float4 as1 = *reinterpret_cast<const float4*>(&asrc[c0 + 4]);
  float4 ad0 = *reinterpret_cast<const float4*>(&adst[c0]);
  float4 ad1 = *reinterpret_cast<const float4*>(&adst[c0 + 4]);
  float asv[8] = {as0.x, as0.y, as0.z, as0.w, as1.x, as1.y, as1.z, as1.w};
  float adv[8] = {ad0.x, ad0.y, ad0.z, ad0.w, ad1.x, ad1.y, ad1.z, ad1.w};

  #pragma unroll
  for (int i = 0; i < 4; i++) {
    int grow = rowbase + r0 + i;
    float ps = 0.f, pd = 0.f;
    #pragma unroll
    for (int j = 0; j < 8; j++) {
      ps = fmaf(acc[i][j], asv[j], ps);
      pd = fmaf(acc[i][j], adv[j], pd);
    }
    // reduce across the 16-lane row group (lane bits 0..3)
    #pragma unroll
    for (int off = 1; off < 16; off <<= 1) {
      ps += __shfl_xor(ps, off);
      pd += __shfl_xor(pd, off);
    }
    if (grow < N_NODES) {
      if (cg == 0) {
        alpha_s[grow] = ps;
        alpha_d[grow] = pd;
      }
      *reinterpret_cast<float4*>(&H[(size_t)grow * D + c0]) =
          make_float4(acc[i][0], acc[i][1], acc[i][2], acc[i][3]);
      *reinterpret_cast<float4*>(&H[(size_t)grow * D + c0 + 4]) =
          make_float4(acc[i][4], acc[i][5], acc[i][6], acc[i][7]);
    }
  }
}

// ---------------- fused segment softmax + aggregate + bias + relu ----------------
template <int FINAL>
__global__ __launch_bounds__(256) void k_agg(const float* __restrict__ H,
                                             const int* __restrict__ rowptr,
                                             const int* __restrict__ col,
                                             const float* __restrict__ alpha_s,
                                             const float* __restrict__ alpha_d,
                                             const float* __restrict__ bias,
                                             float* __restrict__ Out,
                                             const float* __restrict__ fcW,
                                             float* __restrict__ ynode) {
  __shared__ float wls[4][MAXDEG];
  __shared__ int cls[4][MAXDEG];
  int wid = threadIdx.x >> 6;
  int lane = threadIdx.x & 63;
  int node = blockIdx.x * 4 + wid;
  if (node >= N_NODES) return;
  int start = rowptr[node], end = rowptr[node + 1];
  int deg = end - start;
  float ad = alpha_d[node];

  // pass 1: e into registers (lane-strided) + cols into LDS, wave max
  float earr[4];
  float m = -1e30f;
  #pragma unroll
  for (int k = 0; k < 4; ++k) {
    int j0 = lane + k * 64;
    earr[k] = -1e30f;
    if (j0 < deg) {
      int s = col[start + j0];
      float e = alpha_s[s] + ad;
      e = e >= 0.f ? e : NEG_SLOPE * e;
      cls[wid][j0] = s;
      earr[k] = e;
    }
  }
  m = fmaxf(fmaxf(earr[0], earr[1]), fmaxf(earr[2], earr[3]));
  for (int j0 = MAXDEG + lane; j0 < deg; j0 += 64) {   // cold fallback
    int s = col[start + j0];
    float e = alpha_s[s] + ad;
    e = e >= 0.f ? e : NEG_SLOPE * e;
    m = fmaxf(m, e);
  }
  m = wave_max(m);

  // pass 2: weights into LDS, wave sum
  float dsum = 0.f;
  #pragma unroll
  for (int k = 0; k < 4; ++k) {
    int j0 = lane + k * 64;
    if (j0 < deg) {
      float w = expf(earr[k] - m);
      wls[wid][j0] = w;
      dsum += w;
    }
  }
  for (int j0 = MAXDEG + lane; j0 < deg; j0 += 64) {   // cold fallback
    int s = col[start + j0];
    float e = alpha_s[s] + ad;
    e = e >= 0.f ? e : NEG_SLOPE * e;
    dsum += expf(e - m);
  }
  dsum = wave_sum(dsum);
  float inv = 1.f / (dsum + 1e-16f);

  // pass 3: gather, 8 independent row loads per step (weights via LDS broadcast)
  float2 acc = make_float2(0.f, 0.f);
  int degc = deg < MAXDEG ? deg : MAXDEG;
  int jj = 0;
  for (; jj + 8 <= degc; jj += 8) {
    float w[8];
    float2 hv[8];
    #pragma unroll
    for (int u = 0; u < 8; ++u) {
      int s = cls[wid][jj + u];
      w[u] = wls[wid][jj + u];
      hv[u] = *reinterpret_cast<const float2*>(&H[(size_t)s * D + lane * 2]);
    }
    #pragma unroll
    for (int u = 0; u < 8; ++u) {
      acc.x = fmaf(w[u], hv[u].x, acc.x);
      acc.y = fmaf(w[u], hv[u].y, acc.y);
    }
  }
  for (; jj < deg; ++jj) {
    int s;
    float w;
    if (jj < MAXDEG) {
      s = cls[wid][jj];
      w = wls[wid][jj];
    } else {                                            // cold fallback
      s = col[start + jj];
      float e = alpha_s[s] + ad;
      e = e >= 0.f ? e : NEG_SLOPE * e;
      w = expf(e - m);
    }
    float2 hv = *reinterpret_cast<const float2*>(&H[(size_t)s * D + lane * 2]);
    acc.x = fmaf(w, hv.x, acc.x);
    acc.y = fmaf(w, hv.y, acc.y);
  }

  float2 bv = *reinterpret_cast<const float2*>(&bias[lane * 2]);
  float ox = fmaxf(acc.x * inv + bv.x, 0.f);
  float oy = fmaxf(acc.y * inv + bv.y, 0.f);
  if (FINAL) {
    float2 wv = *reinterpret_cast<const float2*>(&fcW[lane * 2]);
    float y = wave_sum(ox * wv.x + oy * wv.y);
    if (lane == 0) ynode[node] = y;
  } else {
    *reinterpret_cast<float2*>(&Out[(size_t)node * D + lane * 2]) = make_float2(ox, oy);
  }
}

// ---------------- finalize: per-graph mean of ynode + bias ----------------
__global__ __launch_bounds__(256) void k_final(const float* __restrict__ ynode,
                                               const int* __restrict__ batch,
                                               const float* __restrict__ fcb,
                                               float* __restrict__ out) {
  __shared__ float sm[256];
  int b = blockIdx.x;
  int tid = threadIdx.x;
  int lo = 0, hi = N_NODES;
  while (lo < hi) { int mid = (lo + hi) >> 1; if (batch[mid] < b) lo = mid + 1; else hi = mid; }
  int s0 = lo;
  lo = 0; hi = N_NODES;
  while (lo < hi) { int mid = (lo + hi) >> 1; if (batch[mid] < b + 1) lo = mid + 1; else hi = mid; }
  int s1 = lo;
  float sum = 0.f;
  for (int n = s0 + tid; n < s1; n += 256) sum += ynode[n];
  sm[tid] = sum;
  __syncthreads();
  #pragma unroll
  for (int off = 128; off > 0; off >>= 1) {
    if (tid < off) sm[tid] += sm[tid + off];
    __syncthreads();
  }
  if (tid == 0) out[b] = sm[0] / fmaxf((float)(s1 - s0), 1.f) + fcb[0];
}

extern "C" void kernel_launch(void* const* d_in, const int* in_sizes, int n_in,
                              void* d_out, int out_size, void* d_ws, size_t ws_size,
                              hipStream_t stream) {
  const float* x = (const float*)d_in[0];
  const int* ei = (const int*)d_in[1];
  const int* batch = (const int*)d_in[2];
  const float* W[4]   = {(const float*)d_in[3], (const float*)d_in[7],
                         (const float*)d_in[11], (const float*)d_in[15]};
  const float* asr[4] = {(const float*)d_in[4], (const float*)d_in[8],
                         (const float*)d_in[12], (const float*)d_in[16]};
  const float* adt[4] = {(const float*)d_in[5], (const float*)d_in[9],
                         (const float*)d_in[13], (const float*)d_in[17]};
  const float* bs[4]  = {(const float*)d_in[6], (const float*)d_in[10],
                         (const float*)d_in[14], (const float*)d_in[18]};
  const float* fcW = (const float*)d_in[19];
  const float* fcb = (const float*)d_in[20];
  float* out = (float*)d_out;

  char* ws = (char*)d_ws;
  size_t off = 0;
  float* hA = (float*)(ws + off); off += (size_t)N_NODES * D * 4;     // gemm out
  float* hB = (float*)(ws + off); off += (size_t)N_NODES * D * 4;     // layer out
  float* alpha_s = (float*)(ws + off); off += (size_t)N_NODES * 4;
  float* alpha_d = (float*)(ws + off); off += (size_t)N_NODES * 4;
  int* cnt  = (int*)(ws + off); off += (size_t)N_NODES * 4;
  int* fill = (int*)(ws + off); off += (size_t)N_NODES * 4;           // contiguous after cnt
  int* rowptr = (int*)(ws + off); off += (size_t)(N_NODES + 1) * 4 + 12;
  int* col = (int*)(ws + off); off += (size_t)E_TOT * 4;
  float* ynode = (float*)(ws + off); off += (size_t)N_NODES * 4;
  int* partial = (int*)(ws + off); off += (size_t)SCAN_GRID * 4;
  (void)ws_size; (void)in_sizes; (void)n_in; (void)out_size;

  hipMemsetAsync(cnt, 0, (size_t)N_NODES * 4 * 2, stream);  // zero cnt + fill
  int eb = (E_TOT + 255) / 256;
  k_count<<<eb, 256, 0, stream>>>(ei, cnt);
  k_scan1<<<SCAN_GRID, SCAN_BLK, 0, stream>>>(cnt, rowptr, partial);
  k_scan2<<<1, 64, 0, stream>>>(partial);
  k_scan3<<<SCAN_GRID, SCAN_BLK, 0, stream>>>(rowptr, partial);
  k_fill<<<eb, 256, 0, stream>>>(ei, rowptr, fill, col);

  const float* in = x;
  for (int l = 0; l < 4; ++l) {
    k_gemm<<<(N_NODES + 63) / 64, 256, 0, stream>>>(in, W[l], hA, asr[l], adt[l],
                                                    alpha_s, alpha_d);
    if (l < 3) {
      k_agg<0><<<(N_NODES + 3) / 4, 256, 0, stream>>>(hA, rowptr, col, alpha_s, alpha_d,
                                                      bs[l], hB, nullptr, nullptr);
    } else {
      k_agg<1><<<(N_NODES + 3) / 4, 256, 0, stream>>>(hA, rowptr, col, alpha_s, alpha_d,
                                                      bs[l], nullptr, fcW, ynode);
    }
    in = hB;
  }
  k_final<<<N_GRAPHS, 256, 0, stream>>>(ynode, batch, fcb, out);
}

// Round 5
// 420.130 us; speedup vs baseline: 2.4783x; 1.1212x over previous
//
#include <hip/hip_runtime.h>

#define N_NODES 50000
#define N_EDGES 800000
#define E_TOT (N_EDGES + N_NODES)
#define D 128
#define N_GRAPHS 64
#define NEG_SLOPE 0.2f
#define MAXDEG 256
#define SCAN_BLK 1024
#define SCAN_GRID ((N_NODES + SCAN_BLK - 1) / SCAN_BLK)   // 49

typedef _Float16 f16x8 __attribute__((ext_vector_type(8)));
typedef float f32x4 __attribute__((ext_vector_type(4)));

__device__ __forceinline__ float wave_max(float v) {
  #pragma unroll
  for (int off = 32; off > 0; off >>= 1) v = fmaxf(v, __shfl_xor(v, off));
  return v;
}
__device__ __forceinline__ float wave_sum(float v) {
  #pragma unroll
  for (int off = 32; off > 0; off >>= 1) v += __shfl_xor(v, off);
  return v;
}

// ---------------- CSR build ----------------
__global__ void k_count(const int* __restrict__ ei, int* __restrict__ cnt) {
  int e = blockIdx.x * blockDim.x + threadIdx.x;
  if (e >= E_TOT) return;
  int dst = (e < N_EDGES) ? ei[N_EDGES + e] : (e - N_EDGES);
  atomicAdd(&cnt[dst], 1);
}

__global__ __launch_bounds__(SCAN_BLK) void k_scan1(const int* __restrict__ cnt,
                                                    int* __restrict__ rowptr,
                                                    int* __restrict__ partial) {
  __shared__ int sm[SCAN_BLK];
  int i = blockIdx.x * SCAN_BLK + threadIdx.x;
  int v = (i < N_NODES) ? cnt[i] : 0;
  sm[threadIdx.x] = v;
  __syncthreads();
  #pragma unroll
  for (int off = 1; off < SCAN_BLK; off <<= 1) {
    int t = (threadIdx.x >= off) ? sm[threadIdx.x - off] : 0;
    __syncthreads();
    sm[threadIdx.x] += t;
    __syncthreads();
  }
  if (i < N_NODES) rowptr[i + 1] = sm[threadIdx.x];
  if (threadIdx.x == SCAN_BLK - 1) partial[blockIdx.x] = sm[threadIdx.x];
}

__global__ void k_scan2(int* __restrict__ partial) {
  int lane = threadIdx.x;
  int v = (lane < SCAN_GRID) ? partial[lane] : 0;
  #pragma unroll
  for (int off = 1; off < 64; off <<= 1) {
    int t = __shfl_up(v, off);
    if (lane >= off) v += t;
  }
  if (lane < SCAN_GRID) partial[lane] = v;
}

__global__ __launch_bounds__(SCAN_BLK) void k_scan3(int* __restrict__ rowptr,
                                                    const int* __restrict__ partial) {
  int i = blockIdx.x * SCAN_BLK + threadIdx.x;
  if (i == 0) rowptr[0] = 0;
  if (i < N_NODES && blockIdx.x > 0) rowptr[i + 1] += partial[blockIdx.x - 1];
}

__global__ void k_fill(const int* __restrict__ ei, const int* __restrict__ rowptr,
                       int* __restrict__ fill, int* __restrict__ col) {
  int e = blockIdx.x * blockDim.x + threadIdx.x;
  if (e >= E_TOT) return;
  int src, dst;
  if (e < N_EDGES) { src = ei[e]; dst = ei[N_EDGES + e]; }
  else { src = e - N_EDGES; dst = src; }
  int pos = rowptr[dst] + atomicAdd(&fill[dst], 1);
  col[pos] = src;
}

// ---------------- W -> fp16 hi/lo fragment-order conversion ----------------
// layout (halves): idx = (n>>4)*2048 + (k>>3)*128 + (n&15)*8 + (k&7)
__global__ __launch_bounds__(256) void k_wconv(const float* __restrict__ W,
                                               _Float16* __restrict__ Wh,
                                               _Float16* __restrict__ Wl) {
  int e = blockIdx.x * 256 + threadIdx.x;   // 0..16383
  int k = e >> 7, n = e & 127;
  float v = W[e];
  _Float16 h = (_Float16)v;
  _Float16 lo = (_Float16)(v - (float)h);
  int idx = (n >> 4) * 2048 + (k >> 3) * 128 + (n & 15) * 8 + (k & 7);
  Wh[idx] = h;
  Wl[idx] = lo;
}

// ---------------- GEMM via fp16x2 split MFMA + fused alpha dots ----------------
// 64 rows x 128 cols per block, 4 waves, wave w owns rows [w*16, w*16+16).
__global__ __launch_bounds__(256) void k_gemm_mfma(const float* __restrict__ X,
                                                   const _Float16* __restrict__ Whf,
                                                   const _Float16* __restrict__ Wlf,
                                                   float* __restrict__ H,
                                                   const float* __restrict__ asrc,
                                                   const float* __restrict__ adst,
                                                   float* __restrict__ alpha_s,
                                                   float* __restrict__ alpha_d) {
  __shared__ __align__(16) _Float16 AhL[8192];   // [w][kgf][r16][8]
  __shared__ __align__(16) _Float16 AlL[8192];
  const int tid = threadIdx.x;
  const int l = tid & 63;
  const int w = tid >> 6;
  const int rowbase = blockIdx.x * 64;

  // stage X tile -> fp16 hi/lo in fragment order
  #pragma unroll
  for (int p = 0; p < 4; ++p) {
    int row = p * 16 + (tid >> 4);       // 0..63
    int k0 = (tid & 15) * 8;
    int grow = rowbase + row;
    float xv[8];
    if (grow < N_NODES) {
      float4 f0 = *reinterpret_cast<const float4*>(&X[(size_t)grow * D + k0]);
      float4 f1 = *reinterpret_cast<const float4*>(&X[(size_t)grow * D + k0 + 4]);
      xv[0] = f0.x; xv[1] = f0.y; xv[2] = f0.z; xv[3] = f0.w;
      xv[4] = f1.x; xv[5] = f1.y; xv[6] = f1.z; xv[7] = f1.w;
    } else {
      #pragma unroll
      for (int j = 0; j < 8; ++j) xv[j] = 0.f;
    }
    f16x8 ah, al;
    #pragma unroll
    for (int j = 0; j < 8; ++j) {
      ah[j] = (_Float16)xv[j];
      al[j] = (_Float16)(xv[j] - (float)ah[j]);
    }
    int idx = (((row >> 4) * 16 + (k0 >> 3)) * 16 + (row & 15)) * 8;
    *reinterpret_cast<f16x8*>(&AhL[idx]) = ah;
    *reinterpret_cast<f16x8*>(&AlL[idx]) = al;
  }
  __syncthreads();

  f32x4 acc[8];
  #pragma unroll
  for (int cc = 0; cc < 8; ++cc) acc[cc] = (f32x4){0.f, 0.f, 0.f, 0.f};

  #pragma unroll
  for (int kt = 0; kt < 4; ++kt) {
    int aidx = w * 2048 + kt * 512 + l * 8;
    f16x8 ah = *reinterpret_cast<const f16x8*>(&AhL[aidx]);
    f16x8 al = *reinterpret_cast<const f16x8*>(&AlL[aidx]);
    #pragma unroll
    for (int cc = 0; cc < 8; ++cc) {
      int bidx = cc * 2048 + kt * 512 + l * 8;
      f16x8 bh = *reinterpret_cast<const f16x8*>(&Whf[bidx]);
      f16x8 bl = *reinterpret_cast<const f16x8*>(&Wlf[bidx]);
      acc[cc] = __builtin_amdgcn_mfma_f32_16x16x32_f16(ah, bh, acc[cc], 0, 0, 0);
      acc[cc] = __builtin_amdgcn_mfma_f32_16x16x32_f16(ah, bl, acc[cc], 0, 0, 0);
      acc[cc] = __builtin_amdgcn_mfma_f32_16x16x32_f16(al, bh, acc[cc], 0, 0, 0);
    }
  }

  // epilogue: store H + fused alpha dots. C/D: col = l&15, row = (l>>4)*4 + reg
  const int myn = l & 15;
  const int rg4 = l >> 4;
  float asv[8], adv[8];
  #pragma unroll
  for (int cc = 0; cc < 8; ++cc) {
    asv[cc] = asrc[cc * 16 + myn];
    adv[cc] = adst[cc * 16 + myn];
  }
  #pragma unroll
  for (int reg = 0; reg < 4; ++reg) {
    int grow = rowbase + w * 16 + rg4 * 4 + reg;
    float ps = 0.f, pd = 0.f;
    #pragma unroll
    for (int cc = 0; cc < 8; ++cc) {
      float v = acc[cc][reg];
      ps = fmaf(v, asv[cc], ps);
      pd = fmaf(v, adv[cc], pd);
      if (grow < N_NODES) H[(size_t)grow * D + cc * 16 + myn] = v;
    }
    #pragma unroll
    for (int off = 1; off < 16; off <<= 1) {
      ps += __shfl_xor(ps, off);
      pd += __shfl_xor(pd, off);
    }
    if (grow < N_NODES && myn == 0) {
      alpha_s[grow] = ps;
      alpha_d[grow] = pd;
    }
  }
}

// ---------------- fused segment softmax + aggregate + bias + relu ----------------
template <int FINAL>
__global__ __launch_bounds__(256) void k_agg(const float* __restrict__ H,
                                             const int* __restrict__ rowptr,
                                             const int* __restrict__ col,
                                             const float* __restrict__ alpha_s,
                                             const float* __restrict__ alpha_d,
                                             const float* __restrict__ bias,
                                             float* __restrict__ Out,
                                             const float* __restrict__ fcW,
                                             float* __restrict__ ynode) {
  __shared__ float wls[4][MAXDEG];
  __shared__ int cls[4][MAXDEG];
  int wid = threadIdx.x >> 6;
  int lane = threadIdx.x & 63;
  int node = blockIdx.x * 4 + wid;
  if (node >= N_NODES) return;
  int start = rowptr[node], end = rowptr[node + 1];
  int deg = end - start;
  float ad = alpha_d[node];

  // pass 1: e into registers + cols into LDS, wave max
  float earr[4];
  float m = -1e30f;
  #pragma unroll
  for (int k = 0; k < 4; ++k) {
    int j0 = lane + k * 64;
    earr[k] = -1e30f;
    if (j0 < deg) {
      int s = col[start + j0];
      float e = alpha_s[s] + ad;
      e = e >= 0.f ? e : NEG_SLOPE * e;
      cls[wid][j0] = s;
      earr[k] = e;
    }
  }
  m = fmaxf(fmaxf(earr[0], earr[1]), fmaxf(earr[2], earr[3]));
  for (int j0 = MAXDEG + lane; j0 < deg; j0 += 64) {
    int s = col[start + j0];
    float e = alpha_s[s] + ad;
    e = e >= 0.f ? e : NEG_SLOPE * e;
    m = fmaxf(m, e);
  }
  m = wave_max(m);

  // pass 2: weights into LDS, wave sum
  float dsum = 0.f;
  #pragma unroll
  for (int k = 0; k < 4; ++k) {
    int j0 = lane + k * 64;
    if (j0 < deg) {
      float w = expf(earr[k] - m);
      wls[wid][j0] = w;
      dsum += w;
    }
  }
  for (int j0 = MAXDEG + lane; j0 < deg; j0 += 64) {
    int s = col[start + j0];
    float e = alpha_s[s] + ad;
    e = e >= 0.f ? e : NEG_SLOPE * e;
    dsum += expf(e - m);
  }
  dsum = wave_sum(dsum);
  float inv = 1.f / (dsum + 1e-16f);

  // pass 3: gather in masked batches of 8 (8 loads in flight, no serial tail)
  float2 acc = make_float2(0.f, 0.f);
  int degc = deg < MAXDEG ? deg : MAXDEG;
  for (int jj = 0; jj < degc; jj += 8) {
    float w[8];
    float2 hv[8];
    #pragma unroll
    for (int u = 0; u < 8; ++u) {
      int idx = jj + u;
      bool ok = idx < degc;
      int s = ok ? cls[wid][idx] : cls[wid][0];
      w[u] = ok ? wls[wid][idx] : 0.f;
      hv[u] = *reinterpret_cast<const float2*>(&H[(size_t)s * D + lane * 2]);
    }
    #pragma unroll
    for (int u = 0; u < 8; ++u) {
      acc.x = fmaf(w[u], hv[u].x, acc.x);
      acc.y = fmaf(w[u], hv[u].y, acc.y);
    }
  }
  for (int jj = MAXDEG; jj < deg; ++jj) {   // cold fallback
    int s = col[start + jj];
    float e = alpha_s[s] + ad;
    e = e >= 0.f ? e : NEG_SLOPE * e;
    float w = expf(e - m);
    float2 hv = *reinterpret_cast<const float2*>(&H[(size_t)s * D + lane * 2]);
    acc.x = fmaf(w, hv.x, acc.x);
    acc.y = fmaf(w, hv.y, acc.y);
  }

  float2 bv = *reinterpret_cast<const float2*>(&bias[lane * 2]);
  float ox = fmaxf(acc.x * inv + bv.x, 0.f);
  float oy = fmaxf(acc.y * inv + bv.y, 0.f);
  if (FINAL) {
    float2 wv = *reinterpret_cast<const float2*>(&fcW[lane * 2]);
    float y = wave_sum(ox * wv.x + oy * wv.y);
    if (lane == 0) ynode[node] = y;
  } else {
    *reinterpret_cast<float2*>(&Out[(size_t)node * D + lane * 2]) = make_float2(ox, oy);
  }
}

// ---------------- finalize: per-graph mean of ynode + bias ----------------
__global__ __launch_bounds__(256) void k_final(const float* __restrict__ ynode,
                                               const int* __restrict__ batch,
                                               const float* __restrict__ fcb,
                                               float* __restrict__ out) {
  __shared__ float sm[256];
  int b = blockIdx.x;
  int tid = threadIdx.x;
  int lo = 0, hi = N_NODES;
  while (lo < hi) { int mid = (lo + hi) >> 1; if (batch[mid] < b) lo = mid + 1; else hi = mid; }
  int s0 = lo;
  lo = 0; hi = N_NODES;
  while (lo < hi) { int mid = (lo + hi) >> 1; if (batch[mid] < b + 1) lo = mid + 1; else hi = mid; }
  int s1 = lo;
  float sum = 0.f;
  for (int n = s0 + tid; n < s1; n += 256) sum += ynode[n];
  sm[tid] = sum;
  __syncthreads();
  #pragma unroll
  for (int off = 128; off > 0; off >>= 1) {
    if (tid < off) sm[tid] += sm[tid + off];
    __syncthreads();
  }
  if (tid == 0) out[b] = sm[0] / fmaxf((float)(s1 - s0), 1.f) + fcb[0];
}

extern "C" void kernel_launch(void* const* d_in, const int* in_sizes, int n_in,
                              void* d_out, int out_size, void* d_ws, size_t ws_size,
                              hipStream_t stream) {
  const float* x = (const float*)d_in[0];
  const int* ei = (const int*)d_in[1];
  const int* batch = (const int*)d_in[2];
  const float* W[4]   = {(const float*)d_in[3], (const float*)d_in[7],
                         (const float*)d_in[11], (const float*)d_in[15]};
  const float* asr[4] = {(const float*)d_in[4], (const float*)d_in[8],
                         (const float*)d_in[12], (const float*)d_in[16]};
  const float* adt[4] = {(const float*)d_in[5], (const float*)d_in[9],
                         (const float*)d_in[13], (const float*)d_in[17]};
  const float* bs[4]  = {(const float*)d_in[6], (const float*)d_in[10],
                         (const float*)d_in[14], (const float*)d_in[18]};
  const float* fcW = (const float*)d_in[19];
  const float* fcb = (const float*)d_in[20];
  float* out = (float*)d_out;

  char* ws = (char*)d_ws;
  size_t off = 0;
  float* hA = (float*)(ws + off); off += (size_t)N_NODES * D * 4;
  float* hB = (float*)(ws + off); off += (size_t)N_NODES * D * 4;
  float* alpha_s = (float*)(ws + off); off += (size_t)N_NODES * 4;
  float* alpha_d = (float*)(ws + off); off += (size_t)N_NODES * 4;
  int* cnt  = (int*)(ws + off); off += (size_t)N_NODES * 4;
  int* fill = (int*)(ws + off); off += (size_t)N_NODES * 4;
  int* rowptr = (int*)(ws + off); off += (size_t)(N_NODES + 1) * 4 + 12;
  int* col = (int*)(ws + off); off += (size_t)E_TOT * 4;
  float* ynode = (float*)(ws + off); off += (size_t)N_NODES * 4;
  int* partial = (int*)(ws + off); off += ((size_t)SCAN_GRID * 4 + 15) & ~15ull;
  _Float16* Whf[4];
  _Float16* Wlf[4];
  for (int lyr = 0; lyr < 4; ++lyr) {
    Whf[lyr] = (_Float16*)(ws + off); off += (size_t)D * D * 2;
    Wlf[lyr] = (_Float16*)(ws + off); off += (size_t)D * D * 2;
  }
  (void)ws_size; (void)in_sizes; (void)n_in; (void)out_size;

  hipMemsetAsync(cnt, 0, (size_t)N_NODES * 4 * 2, stream);  // zero cnt + fill
  for (int lyr = 0; lyr < 4; ++lyr)
    k_wconv<<<64, 256, 0, stream>>>(W[lyr], Whf[lyr], Wlf[lyr]);
  int eb = (E_TOT + 255) / 256;
  k_count<<<eb, 256, 0, stream>>>(ei, cnt);
  k_scan1<<<SCAN_GRID, SCAN_BLK, 0, stream>>>(cnt, rowptr, partial);
  k_scan2<<<1, 64, 0, stream>>>(partial);
  k_scan3<<<SCAN_GRID, SCAN_BLK, 0, stream>>>(rowptr, partial);
  k_fill<<<eb, 256, 0, stream>>>(ei, rowptr, fill, col);

  const float* in = x;
  for (int l = 0; l < 4; ++l) {
    k_gemm_mfma<<<(N_NODES + 63) / 64, 256, 0, stream>>>(in, Whf[l], Wlf[l], hA,
                                                         asr[l], adt[l], alpha_s, alpha_d);
    if (l < 3) {
      k_agg<0><<<(N_NODES + 3) / 4, 256, 0, stream>>>(hA, rowptr, col, alpha_s, alpha_d,
                                                      bs[l], hB, nullptr, nullptr);
    } else {
      k_agg<1><<<(N_NODES + 3) / 4, 256, 0, stream>>>(hA, rowptr, col, alpha_s, alpha_d,
                                                      bs[l], nullptr, fcW, ynode);
    }
    in = hB;
  }
  k_final<<<N_GRAPHS, 256, 0, stream>>>(ynode, batch, fcb, out);
}